// Round 1
// baseline (819.709 us; speedup 1.0000x reference)
//
#include <hip/hip_runtime.h>

#define HIDDEN 51
#define LSEQ 1000

// One wave (64 lanes) per batch element. Lane m (m < 51) owns gate rows
// {m, m+51, m+102, m+153} = (i, f, g, o) for hidden index m, so the c/h
// update is lane-local. U_w rows are held in VGPRs (204 regs/lane);
// __launch_bounds__(64,1) allows up to 512 VGPRs -> no spill, 1 wave/SIMD.
// h_k broadcast each step via v_readlane (SGPR operand feeds 4 FMAs).
__global__ __launch_bounds__(64, 1) void lstm_seq_kernel(
    const float* __restrict__ x,
    const float* __restrict__ W_w,
    const float* __restrict__ W_b,
    const float* __restrict__ U_w,
    const float* __restrict__ U_b,
    const float* __restrict__ lin_w,
    const float* __restrict__ lin_b,
    float* __restrict__ out)
{
    const int b    = blockIdx.x;
    const int lane = threadIdx.x;      // 0..63
    const bool active = lane < HIDDEN; // lanes 51..63 compute zeros
    const int m = active ? lane : 0;

    const int j0 = m;
    const int j1 = m + HIDDEN;
    const int j2 = m + 2 * HIDDEN;
    const int j3 = m + 3 * HIDDEN;

    // Per-lane weights (registers).
    float ww0 = W_w[j0], ww1 = W_w[j1], ww2 = W_w[j2], ww3 = W_w[j3];
    float bb0 = W_b[j0] + U_b[j0];
    float bb1 = W_b[j1] + U_b[j1];
    float bb2 = W_b[j2] + U_b[j2];
    float bb3 = W_b[j3] + U_b[j3];
    float lw  = lin_w[m];

    float U0[HIDDEN], U1[HIDDEN], U2[HIDDEN], U3[HIDDEN];
#pragma unroll
    for (int k = 0; k < HIDDEN; ++k) {
        U0[k] = U_w[j0 * HIDDEN + k];
        U1[k] = U_w[j1 * HIDDEN + k];
        U2[k] = U_w[j2 * HIDDEN + k];
        U3[k] = U_w[j3 * HIDDEN + k];
    }

    if (!active) {
        ww0 = ww1 = ww2 = ww3 = 0.f;
        bb0 = bb1 = bb2 = bb3 = 0.f;
        lw = 0.f;
#pragma unroll
        for (int k = 0; k < HIDDEN; ++k) { U0[k] = U1[k] = U2[k] = U3[k] = 0.f; }
    }

    const float lb = lin_b[0];

    float h = 0.f, c = 0.f;
    const float* __restrict__ xrow = x + (long)b * LSEQ;
    float* __restrict__ orow = out + (long)b * LSEQ;

    float x_cur = xrow[0];   // wave-uniform -> scalar load
    for (int t = 0; t < LSEQ; ++t) {
        // Prefetch next x (uniform scalar load), hidden under the FMA block.
        const int tn = (t + 1 < LSEQ) ? (t + 1) : t;
        float x_next = xrow[tn];

        float gi = fmaf(x_cur, ww0, bb0);
        float gf = fmaf(x_cur, ww1, bb1);
        float gg = fmaf(x_cur, ww2, bb2);
        float go = fmaf(x_cur, ww3, bb3);

#pragma unroll
        for (int k = 0; k < HIDDEN; ++k) {
            // Broadcast h_k: constant-index readlane -> SGPR, legal FMA operand.
            float hk = __builtin_bit_cast(
                float, __builtin_amdgcn_readlane(__builtin_bit_cast(int, h), k));
            gi = fmaf(hk, U0[k], gi);
            gf = fmaf(hk, U1[k], gf);
            gg = fmaf(hk, U2[k], gg);
            go = fmaf(hk, U3[k], go);
        }

        // NOTE: faithful to reference — no sigmoid on gates.
        c = fmaf(gf, c, gi * gg);
        float th = tanhf(c);
        h = go * th;

        // out[b,t] = sum_m h_m * lin_w[m] + lin_b  (lanes >= 51 contribute 0)
        float prod = h * lw;
#pragma unroll
        for (int off = 32; off > 0; off >>= 1)
            prod += __shfl_xor(prod, off, 64);
        if (lane == 0) orow[t] = prod + lb;

        x_cur = x_next;
    }
}

extern "C" void kernel_launch(void* const* d_in, const int* in_sizes, int n_in,
                              void* d_out, int out_size, void* d_ws, size_t ws_size,
                              hipStream_t stream) {
    const float* x     = (const float*)d_in[0];
    const float* W_w   = (const float*)d_in[1];
    const float* W_b   = (const float*)d_in[2];
    const float* U_w   = (const float*)d_in[3];
    const float* U_b   = (const float*)d_in[4];
    const float* lin_w = (const float*)d_in[5];
    const float* lin_b = (const float*)d_in[6];
    // d_in[7] = future (static 0 in this problem; out_size == B*LSEQ)
    float* out = (float*)d_out;

    const int B = in_sizes[0] / LSEQ;  // 1024
    lstm_seq_kernel<<<dim3(B), dim3(64), 0, stream>>>(
        x, W_w, W_b, U_w, U_b, lin_w, lin_b, out);
}

// Round 2
// 714.928 us; speedup vs baseline: 1.1466x; 1.1466x over previous
//
#include <hip/hip_runtime.h>

#define HIDDEN 51
#define LSEQ 1000

// Branch-free tanh: tanh(v) = 1 - 2/(exp2(2*log2e*v)+1).
// Saturates to +/-1 for large |v| (exp2->inf => rcp->0; exp2->0 => rcp(1)).
// v_exp_f32 + v_rcp_f32: ~4 instrs vs libm's ~30.
__device__ __forceinline__ float fast_tanh(float v) {
    float e = __builtin_amdgcn_exp2f(v * 2.885390081777927f);  // 2*log2(e)
    float r = __builtin_amdgcn_rcpf(e + 1.0f);
    return fmaf(-2.0f, r, 1.0f);
}

// One wave (64 lanes) per batch element. Lane m (m < 51) owns gate rows
// {m, m+51, m+102, m+153} = (i, f, g, o) for hidden index m, so the c/h
// update is lane-local. U rows live in registers (VGPR+AGPR, unified file).
// h_k broadcast each step via v_readlane (SGPR operand feeds 4 FMAs).
// Output dot for step t is software-pipelined into step t+1 so the 6-deep
// ds_swizzle butterfly hides under the 255-instr FMA block instead of being
// a ~200-cycle exposed serial tail.
__global__ __launch_bounds__(64, 1) void lstm_seq_kernel(
    const float* __restrict__ x,
    const float* __restrict__ W_w,
    const float* __restrict__ W_b,
    const float* __restrict__ U_w,
    const float* __restrict__ U_b,
    const float* __restrict__ lin_w,
    const float* __restrict__ lin_b,
    float* __restrict__ out)
{
    const int b    = blockIdx.x;
    const int lane = threadIdx.x;      // 0..63
    const bool active = lane < HIDDEN; // lanes 51..63 compute zeros
    const int m = active ? lane : 0;

    const int j0 = m;
    const int j1 = m + HIDDEN;
    const int j2 = m + 2 * HIDDEN;
    const int j3 = m + 3 * HIDDEN;

    float ww0 = W_w[j0], ww1 = W_w[j1], ww2 = W_w[j2], ww3 = W_w[j3];
    float bb0 = W_b[j0] + U_b[j0];
    float bb1 = W_b[j1] + U_b[j1];
    float bb2 = W_b[j2] + U_b[j2];
    float bb3 = W_b[j3] + U_b[j3];
    float lw  = lin_w[m];

    float U0[HIDDEN], U1[HIDDEN], U2[HIDDEN], U3[HIDDEN];
#pragma unroll
    for (int k = 0; k < HIDDEN; ++k) {
        U0[k] = U_w[j0 * HIDDEN + k];
        U1[k] = U_w[j1 * HIDDEN + k];
        U2[k] = U_w[j2 * HIDDEN + k];
        U3[k] = U_w[j3 * HIDDEN + k];
    }

    if (!active) {
        ww0 = ww1 = ww2 = ww3 = 0.f;
        bb0 = bb1 = bb2 = bb3 = 0.f;
        lw = 0.f;
#pragma unroll
        for (int k = 0; k < HIDDEN; ++k) { U0[k] = U1[k] = U2[k] = U3[k] = 0.f; }
    }

    const float lb = lin_b[0];

    float h = 0.f, c = 0.f;
    const float* __restrict__ xrow = x + (long)b * LSEQ;
    float* __restrict__ orow = out + (long)b * LSEQ;

    float red = 0.f;          // pending h*lw from previous step (pipelined)
    float x_cur = xrow[0];    // wave-uniform -> scalar load
    for (int t = 0; t < LSEQ; ++t) {
        const int tn = (t + 1 < LSEQ) ? (t + 1) : t;
        float x_next = xrow[tn];

        // Start the 4 independent gate chains (no h dependency).
        float gi = fmaf(x_cur, ww0, bb0);
        float gf = fmaf(x_cur, ww1, bb1);
        float gg = fmaf(x_cur, ww2, bb2);
        float go = fmaf(x_cur, ww3, bb3);

        // Pipelined butterfly for PREVIOUS step's output. Unconditional and
        // in the same BB as the k-loop below -> swizzle latency hides under
        // the FMA issue stream. (t==0 reduces 0 and harmlessly writes lb to
        // orow[0], overwritten by the correct value at t==1.)
        float r = red;
#pragma unroll
        for (int off = 32; off > 0; off >>= 1)
            r += __shfl_xor(r, off, 64);

#pragma unroll
        for (int k = 0; k < HIDDEN; ++k) {
            float hk = __builtin_bit_cast(
                float, __builtin_amdgcn_readlane(__builtin_bit_cast(int, h), k));
            gi = fmaf(hk, U0[k], gi);
            gf = fmaf(hk, U1[k], gf);
            gg = fmaf(hk, U2[k], gg);
            go = fmaf(hk, U3[k], go);
        }

        // NOTE: faithful to reference — no sigmoid on gates.
        c = fmaf(gf, c, gi * gg);
        float th = fast_tanh(c);
        h = go * th;
        red = h * lw;

        // Store previous step's output (off the critical path; BB split only
        // after all compute).
        const int ot = (t > 0) ? (t - 1) : 0;
        if (lane == 0) orow[ot] = r + lb;

        x_cur = x_next;
    }

    // Drain the pipeline: reduction for t = LSEQ-1.
#pragma unroll
    for (int off = 32; off > 0; off >>= 1)
        red += __shfl_xor(red, off, 64);
    if (lane == 0) orow[LSEQ - 1] = red + lb;
}

extern "C" void kernel_launch(void* const* d_in, const int* in_sizes, int n_in,
                              void* d_out, int out_size, void* d_ws, size_t ws_size,
                              hipStream_t stream) {
    const float* x     = (const float*)d_in[0];
    const float* W_w   = (const float*)d_in[1];
    const float* W_b   = (const float*)d_in[2];
    const float* U_w   = (const float*)d_in[3];
    const float* U_b   = (const float*)d_in[4];
    const float* lin_w = (const float*)d_in[5];
    const float* lin_b = (const float*)d_in[6];
    // d_in[7] = future (static 0; out_size == B*LSEQ)
    float* out = (float*)d_out;

    const int B = in_sizes[0] / LSEQ;  // 1024
    lstm_seq_kernel<<<dim3(B), dim3(64), 0, stream>>>(
        x, W_w, W_b, U_w, U_b, lin_w, lin_b, out);
}